// Round 6
// baseline (147.403 us; speedup 1.0000x reference)
//
#include <hip/hip_runtime.h>
#include <hip/hip_bf16.h>

typedef unsigned short u16;
typedef unsigned int u32;
typedef __bf16 bf16x8 __attribute__((ext_vector_type(8)));
typedef float f32x4 __attribute__((ext_vector_type(4)));

#define DMODEL 1024
#define NH 16
#define DH 64
#define BB 2
#define TT 2048
#define MM 4096   // BB*TT
#define NQKV 3072
#define KVB 64    // attention key-tile

// Q pre-scale: Dh^-0.5 * log2(e) -> scores land in log2 domain (P = v_exp_f32 direct)
#define QSCALE 0.18033688011112042f

static __device__ __forceinline__ u16 f2bf(float f) {
  u32 u = __float_as_uint(f);
  u = (u + 0x7FFFu + ((u >> 16) & 1u)) >> 16;  // RNE
  return (u16)u;
}

static __device__ __forceinline__ u32 pk2bf(float a, float b) {
  u16 ua = __builtin_bit_cast(u16, (__bf16)a);
  u16 ub = __builtin_bit_cast(u16, (__bf16)b);
  return (u32)ua | ((u32)ub << 16);
}

static __device__ __forceinline__ float fexp2(float x) {
#if __has_builtin(__builtin_amdgcn_exp2f)
  return __builtin_amdgcn_exp2f(x);
#else
  float r; asm("v_exp_f32 %0, %1" : "=v"(r) : "v"(x)); return r;
#endif
}

static __device__ __forceinline__ float max3f(float a, float b, float c) {
  return fmaxf(fmaxf(a, b), c);  // fuses to v_max3_f32
}

static __device__ __forceinline__ void gload16(const u16* g, u16* l) {
  __builtin_amdgcn_global_load_lds(
      (const __attribute__((address_space(1))) void*)g,
      (__attribute__((address_space(3))) void*)l, 16, 0, 0);
}

// Fused f32->bf16 convert: x | wqkv | wproj (dst regions contiguous in ws).
#define N4X  (MM * DMODEL / 4)
#define N4W  (NQKV * DMODEL / 4)
#define N4P  (DMODEL * DMODEL / 4)
__global__ __launch_bounds__(256) void cvt_all(const float* __restrict__ x,
                                               const float* __restrict__ wqkv,
                                               const float* __restrict__ wproj,
                                               u16* __restrict__ dst) {
  int i = blockIdx.x * 256 + threadIdx.x;
  const float* src;
  int j = i;
  if (i < N4X) {
    src = x;
  } else if (i < N4X + N4W) {
    src = wqkv; j = i - N4X;
  } else {
    src = wproj; j = i - (N4X + N4W);
  }
  float4 v = reinterpret_cast<const float4*>(src)[j];
  ushort4 o;
  o.x = f2bf(v.x); o.y = f2bf(v.y); o.z = f2bf(v.z); o.w = f2bf(v.w);
  reinterpret_cast<ushort4*>(dst)[i] = o;
}

// ---------- GEMM: 128x128 tile, K=1024, 3-buf 2-ahead pipeline, counted vmcnt(4) ----------
static __device__ __forceinline__ void gemm_stage(
    const u16* __restrict__ A, const u16* __restrict__ B, u16* As, u16* Bs,
    int r0, int o0, int r1, int o1, int c0, int c1, int kcol) {
  gload16(A + (size_t)r0 * DMODEL + kcol + o0, As + c0 * 8);
  gload16(A + (size_t)r1 * DMODEL + kcol + o1, As + c1 * 8);
  gload16(B + (size_t)r0 * DMODEL + kcol + o0, Bs + c0 * 8);
  gload16(B + (size_t)r1 * DMODEL + kcol + o1, Bs + c1 * 8);
}

static __device__ __forceinline__ void gemm128_mainloop(
    const u16* __restrict__ Abase, const u16* __restrict__ Bbase,
    u16* As, u16* Bs, f32x4 (&acc)[4][4]) {
  const int tid = threadIdx.x;
  const int lane = tid & 63;
  const int w = tid >> 6;
  const int rowg = lane >> 4, col = lane & 15;
  const int wm = w >> 1, wn = w & 1;
  const int c0 = tid, c1 = tid + 256;
  const int r0 = c0 >> 2, o0 = (c0 & 3) * 8;
  const int r1 = c1 >> 2, o1 = (c1 & 3) * 8;

  // prologue: stage tiles 0,1; retire tile 0 only (tile 1 stays in flight)
  gemm_stage(Abase, Bbase, As, Bs, r0, o0, r1, o1, c0, c1, 0);
  gemm_stage(Abase, Bbase, As + 4096, Bs + 4096, r0, o0, r1, o1, c0, c1, 32);
  asm volatile("s_waitcnt vmcnt(4)" ::: "memory");
  __builtin_amdgcn_s_barrier();

  for (int kt = 0; kt < DMODEL / 32; ++kt) {
    const int kn = ((kt + 2) & (DMODEL / 32 - 1)) * 32;  // wrap keeps addresses in-bounds
    const int sp = ((kt + 2) % 3) * 4096;
    gemm_stage(Abase, Bbase, As + sp, Bs + sp, r0, o0, r1, o1, c0, c1, kn);
    const u16* as = As + (kt % 3) * 4096;
    const u16* bs = Bs + (kt % 3) * 4096;
    bf16x8 af[4], bfr[4];
#pragma unroll
    for (int i = 0; i < 4; ++i)
      af[i] = *reinterpret_cast<const bf16x8*>(as + (wm * 64 + i * 16 + col) * 32 + rowg * 8);
#pragma unroll
    for (int j = 0; j < 4; ++j)
      bfr[j] = *reinterpret_cast<const bf16x8*>(bs + (wn * 64 + j * 16 + col) * 32 + rowg * 8);
#pragma unroll
    for (int i = 0; i < 4; ++i)
#pragma unroll
      for (int j = 0; j < 4; ++j)
        acc[i][j] = __builtin_amdgcn_mfma_f32_16x16x32_bf16(af[i], bfr[j], acc[i][j], 0, 0, 0);
    // retire stage(kt+1) only; stage(kt+2)'s 4 loads stay in flight across the barrier
    asm volatile("s_waitcnt vmcnt(4)" ::: "memory");
    __builtin_amdgcn_s_barrier();
  }
}

// QKV projection: C[m,n] = x[m,:] . Wqkv[n,:]; scatter to q/k/vt, q pre-scaled.
// grid 768 = 3 blocks/CU exactly; LDS 48KB/block -> 144KB/CU at 3 blocks.
__global__ __launch_bounds__(256, 3) void qkv_gemm(
    const u16* __restrict__ xb, const u16* __restrict__ wb,
    u16* __restrict__ qb, u16* __restrict__ kb, u16* __restrict__ vtb) {
  __shared__ u16 As[3 * 128 * 32];
  __shared__ u16 Bs[3 * 128 * 32];
  f32x4 acc[4][4];
#pragma unroll
  for (int i = 0; i < 4; ++i)
#pragma unroll
    for (int j = 0; j < 4; ++j) acc[i][j] = (f32x4){0.f, 0.f, 0.f, 0.f};
  gemm128_mainloop(xb + (size_t)blockIdx.y * 128 * DMODEL,
                   wb + (size_t)blockIdx.x * 128 * DMODEL, As, Bs, acc);
  const int lane = threadIdx.x & 63, w = threadIdx.x >> 6;
  const int rowg = lane >> 4, col = lane & 15, wm = w >> 1, wn = w & 1;
#pragma unroll
  for (int i = 0; i < 4; ++i) {
#pragma unroll
    for (int j = 0; j < 4; ++j) {
#pragma unroll
      for (int r = 0; r < 4; ++r) {
        int m = blockIdx.y * 128 + wm * 64 + i * 16 + rowg * 4 + r;
        int n = blockIdx.x * 128 + wn * 64 + j * 16 + col;
        int b = m >> 11, t = m & (TT - 1);
        int s = n >> 10, h = (n >> 6) & 15, d = n & 63;
        int bh = b * NH + h;
        float v = acc[i][j][r];
        if (s == 0)      qb[((size_t)bh * TT + t) * DH + d] = f2bf(v * QSCALE);
        else if (s == 1) kb[((size_t)bh * TT + t) * DH + d] = f2bf(v);
        else             vtb[((size_t)bh * DH + d) * TT + t] = f2bf(v);
      }
    }
  }
}

// Output projection: out[m,n] = ob[m,:] . Wproj[n,:], f32 out.
__global__ __launch_bounds__(256, 3) void proj_gemm(
    const u16* __restrict__ ab, const u16* __restrict__ wb, float* __restrict__ out) {
  __shared__ u16 As[3 * 128 * 32];
  __shared__ u16 Bs[3 * 128 * 32];
  f32x4 acc[4][4];
#pragma unroll
  for (int i = 0; i < 4; ++i)
#pragma unroll
    for (int j = 0; j < 4; ++j) acc[i][j] = (f32x4){0.f, 0.f, 0.f, 0.f};
  gemm128_mainloop(ab + (size_t)blockIdx.y * 128 * DMODEL,
                   wb + (size_t)blockIdx.x * 128 * DMODEL, As, Bs, acc);
  const int lane = threadIdx.x & 63, w = threadIdx.x >> 6;
  const int rowg = lane >> 4, col = lane & 15, wm = w >> 1, wn = w & 1;
#pragma unroll
  for (int i = 0; i < 4; ++i) {
#pragma unroll
    for (int j = 0; j < 4; ++j) {
#pragma unroll
      for (int r = 0; r < 4; ++r) {
        int m = blockIdx.y * 128 + wm * 64 + i * 16 + rowg * 4 + r;
        int n = blockIdx.x * 128 + wn * 64 + j * 16 + col;
        out[(size_t)m * DMODEL + n] = acc[i][j][r];
      }
    }
  }
}

// ---------- Flash attention, swapped-operand, log2 softmax, 3-buf 2-ahead pipeline ----------
static __device__ __forceinline__ void attn_stage(
    const u16* __restrict__ kbase, const u16* __restrict__ vbase,
    int kt, u16* KsSel, u16* VsSel, int tid) {
#pragma unroll
  for (int p = 0; p < 2; ++p) {
    int c = p * 256 + tid;
    int row = c >> 3;
    int bI = (c & 7) * 16;
    gload16(kbase + kt * (KVB * DH) + row * DH + ((bI ^ ((row & 7) << 4)) >> 1), KsSel + c * 8);
  }
#pragma unroll
  for (int p = 0; p < 2; ++p) {
    int c = p * 256 + tid;
    int d = c >> 3;
    int bI = (c & 7) * 16;
    gload16(vbase + (size_t)d * TT + kt * KVB + ((bI ^ ((d & 7) << 4)) >> 1), VsSel + c * 8);
  }
}

__global__ __launch_bounds__(256, 2) void attn_kernel(
    const u16* __restrict__ qb, const u16* __restrict__ kb,
    const u16* __restrict__ vtb, const unsigned char* __restrict__ mask,
    u16* __restrict__ ob) {
  __shared__ u16 Ks[3][KVB * DH];      // [key][d], swizzled, 3 x 8KB
  __shared__ u16 Vs[3][DH * KVB];      // [d][key], swizzled, 3 x 8KB
  __shared__ u16 Pl[4][32 * KVB];      // per-wave [q][key], swizzled, 4 x 4KB
  __shared__ unsigned char maskb[TT];
  __shared__ u32 mflag;

  const int tid = threadIdx.x;
  const int lane = tid & 63, w = tid >> 6;
  const int rowg = lane >> 4, col = lane & 15;
  const int qt = blockIdx.x, bh = blockIdx.y;
  const int b = bh >> 4;

  if (tid == 0) mflag = 0;
  __syncthreads();

  {
    const u32* mg = reinterpret_cast<const u32*>(mask + (size_t)b * TT);
    u32 m0 = mg[tid * 2], m1 = mg[tid * 2 + 1];
    *reinterpret_cast<u32*>(maskb + tid * 8) = m0;
    *reinterpret_cast<u32*>(maskb + tid * 8 + 4) = m1;
    if (m0 | m1) atomicOr(&mflag, 1u << (tid >> 3));
  }

  const int qrow0 = qt * 128 + w * 32;
  const u16* qptr = qb + ((size_t)bh * TT + qrow0) * DH;
  bf16x8 a_q[2][2];  // [qg][ds] — B-operand frags: col = query, k-slice = d
#pragma unroll
  for (int qg = 0; qg < 2; ++qg)
#pragma unroll
    for (int ds = 0; ds < 2; ++ds)
      a_q[qg][ds] = *reinterpret_cast<const bf16x8*>(qptr + (qg * 16 + col) * DH + ds * 32 + rowg * 8);

  f32x4 acc_o[2][4];         // [qg][df]: query = qg*16+col, d = df*16 + rowg*4 + r
  float m_run[2], l_run[2];  // log2-domain running max / sum
#pragma unroll
  for (int qg = 0; qg < 2; ++qg) {
#pragma unroll
    for (int df = 0; df < 4; ++df) acc_o[qg][df] = (f32x4){0.f, 0.f, 0.f, 0.f};
    m_run[qg] = -1e30f; l_run[qg] = 0.f;
  }

  const u16* kbase = kb + (size_t)bh * TT * DH;
  const u16* vbase = vtb + (size_t)bh * DH * TT;
  u16* pw = Pl[w];

  // prologue: stage tiles 0,1; retire tile 0 (tile 1 in flight); syncthreads also
  // publishes mask bytes + mflag.
  attn_stage(kbase, vbase, 0, Ks[0], Vs[0], tid);
  attn_stage(kbase, vbase, 1, Ks[1], Vs[1], tid);
  asm volatile("s_waitcnt vmcnt(4)" ::: "memory");
  __syncthreads();
  const u32 fm = mflag;

  for (int t = 0; t < TT / KVB; ++t) {
    const int tn2 = (t + 2) & (TT / KVB - 1);  // wrap: in-bounds, uniform vm count
    const int sp = (t + 2) % 3;
    attn_stage(kbase, vbase, tn2, Ks[sp], Vs[sp], tid);

    // ---- S^T = K . Q^T : sc[qg][kf], key = kf*16 + rowg*4 + r, query = qg*16+col ----
    f32x4 sc[2][4];
#pragma unroll
    for (int qg = 0; qg < 2; ++qg)
#pragma unroll
      for (int kf = 0; kf < 4; ++kf) sc[qg][kf] = (f32x4){0.f, 0.f, 0.f, 0.f};
    const u16* ks = Ks[t % 3];
#pragma unroll
    for (int ds = 0; ds < 2; ++ds) {
      bf16x8 ak[4];
#pragma unroll
      for (int kf = 0; kf < 4; ++kf) {
        int krow = kf * 16 + col;
        ak[kf] = *reinterpret_cast<const bf16x8*>(
            ks + krow * DH + (((ds * 64 + rowg * 16) ^ ((krow & 7) << 4)) >> 1));
      }
#pragma unroll
      for (int qg = 0; qg < 2; ++qg)
#pragma unroll
        for (int kf = 0; kf < 4; ++kf)
          sc[qg][kf] = __builtin_amdgcn_mfma_f32_16x16x32_bf16(ak[kf], a_q[qg][ds], sc[qg][kf], 0, 0, 0);
    }

    if (fm & (1u << t)) {  // rare path: per-key additive mask (log2 domain ok)
#pragma unroll
      for (int kf = 0; kf < 4; ++kf)
#pragma unroll
        for (int r = 0; r < 4; ++r) {
          float ma = maskb[t * KVB + kf * 16 + rowg * 4 + r] ? -1e30f : 0.f;
          sc[0][kf][r] += ma;
          sc[1][kf][r] += ma;
        }
    }

    // ---- online softmax: lane-local max (v_max3) + 2 shuffles; defer-rescale THR=8 ----
#pragma unroll
    for (int qg = 0; qg < 2; ++qg) {
      float t0 = max3f(sc[qg][0][0], sc[qg][0][1], sc[qg][0][2]);
      float t1 = max3f(sc[qg][0][3], sc[qg][1][0], sc[qg][1][1]);
      float t2 = max3f(sc[qg][1][2], sc[qg][1][3], sc[qg][2][0]);
      float t3 = max3f(sc[qg][2][1], sc[qg][2][2], sc[qg][2][3]);
      float t4 = max3f(sc[qg][3][0], sc[qg][3][1], sc[qg][3][2]);
      float mx = fmaxf(max3f(t0, t1, t2), max3f(t3, t4, sc[qg][3][3]));
      mx = fmaxf(mx, __shfl_xor(mx, 16, 64));
      mx = fmaxf(mx, __shfl_xor(mx, 32, 64));
      if (__any(mx > m_run[qg] + 8.0f)) {   // T13: rescale only on real max growth
        float mn = fmaxf(m_run[qg], mx);
        float corr = fexp2(m_run[qg] - mn); // 2^(old-new); first tile -> 0
        m_run[qg] = mn;
        l_run[qg] *= corr;
#pragma unroll
        for (int df = 0; df < 4; ++df) acc_o[qg][df] *= corr;
      }
      const float mc = m_run[qg];

      const int q = qg * 16 + col;
      const int sw = (q & 7) << 4;
      u16* prow = pw + q * KVB;
      float rs = 0.f;
#pragma unroll
      for (int kf = 0; kf < 4; ++kf) {
        float p0 = fexp2(sc[qg][kf][0] - mc);
        float p1 = fexp2(sc[qg][kf][1] - mc);
        float p2 = fexp2(sc[qg][kf][2] - mc);
        float p3 = fexp2(sc[qg][kf][3] - mc);
        rs += (p0 + p1) + (p2 + p3);
        uint2 pk;
        pk.x = pk2bf(p0, p1);
        pk.y = pk2bf(p2, p3);
        int bI = kf * 32 + rowg * 8;
        *reinterpret_cast<uint2*>(prow + ((bI ^ sw) >> 1)) = pk;  // ds_write_b64
      }
      rs += __shfl_xor(rs, 16, 64);
      rs += __shfl_xor(rs, 32, 64);
      l_run[qg] += rs;
    }
    asm volatile("s_waitcnt lgkmcnt(0)" ::: "memory");
    __builtin_amdgcn_sched_barrier(0);

    // ---- O^T += V^T . P^T ----
    const u16* vs = Vs[t % 3];
    __builtin_amdgcn_s_setprio(1);
#pragma unroll
    for (int ksI = 0; ksI < 2; ++ksI) {
      bf16x8 bp[2];
#pragma unroll
      for (int qg = 0; qg < 2; ++qg) {
        int q = qg * 16 + col;
        bp[qg] = *reinterpret_cast<const bf16x8*>(
            pw + q * KVB + (((ksI * 64 + rowg * 16) ^ ((q & 7) << 4)) >> 1));
      }
#pragma unroll
      for (int df = 0; df < 4; ++df) {
        int vrow = df * 16 + col;
        bf16x8 bv = *reinterpret_cast<const bf16x8*>(
            vs + vrow * KVB + (((ksI * 64 + rowg * 16) ^ ((vrow & 7) << 4)) >> 1));
#pragma unroll
        for (int qg = 0; qg < 2; ++qg)
          acc_o[qg][df] = __builtin_amdgcn_mfma_f32_16x16x32_bf16(bv, bp[qg], acc_o[qg][df], 0, 0, 0);
      }
    }
    __builtin_amdgcn_s_setprio(0);

    // retire stage(t+1) only; stage(t+2) stays in flight across the barrier
    asm volatile("s_waitcnt vmcnt(4)" ::: "memory");
    __builtin_amdgcn_s_barrier();
  }

  const int h = bh & 15;
#pragma unroll
  for (int qg = 0; qg < 2; ++qg) {
    float inv = 1.f / l_run[qg];
    int tq = qrow0 + qg * 16 + col;
    size_t rowoff = ((size_t)(b * TT + tq)) * DMODEL + h * DH + rowg * 4;
#pragma unroll
    for (int df = 0; df < 4; ++df) {
      ushort4 o4;
      o4.x = f2bf(acc_o[qg][df][0] * inv);
      o4.y = f2bf(acc_o[qg][df][1] * inv);
      o4.z = f2bf(acc_o[qg][df][2] * inv);
      o4.w = f2bf(acc_o[qg][df][3] * inv);
      *reinterpret_cast<ushort4*>(ob + rowoff + df * 16) = o4;
    }
  }
}

extern "C" void kernel_launch(void* const* d_in, const int* in_sizes, int n_in,
                              void* d_out, int out_size, void* d_ws, size_t ws_size,
                              hipStream_t stream) {
  const float* x = (const float*)d_in[0];
  const unsigned char* mask = (const unsigned char*)d_in[1];
  const float* wqkv = (const float*)d_in[2];
  const float* wproj = (const float*)d_in[3];
  float* out = (float*)d_out;

  u16* xb     = (u16*)d_ws;
  u16* wqkvb  = xb    + (size_t)MM * DMODEL;
  u16* wprojb = wqkvb + (size_t)NQKV * DMODEL;
  u16* qb     = wprojb + (size_t)DMODEL * DMODEL;
  u16* kb     = qb + (size_t)MM * DMODEL;
  u16* vtb    = kb + (size_t)MM * DMODEL;
  u16* ob     = vtb + (size_t)MM * DMODEL;

  cvt_all<<<(N4X + N4W + N4P) / 256, 256, 0, stream>>>(x, wqkv, wproj, xb);
  qkv_gemm<<<dim3(NQKV / 128, MM / 128), 256, 0, stream>>>(xb, wqkvb, qb, kb, vtb);
  attn_kernel<<<dim3(TT / 128, BB * NH), 256, 0, stream>>>(qb, kb, vtb, mask, ob);
  proj_gemm<<<dim3(DMODEL / 128, MM / 128), 256, 0, stream>>>(ob, wprojb, out);
}

// Round 7
// 135.133 us; speedup vs baseline: 1.0908x; 1.0908x over previous
//
#include <hip/hip_runtime.h>
#include <hip/hip_bf16.h>

typedef unsigned short u16;
typedef unsigned int u32;
typedef __bf16 bf16x8 __attribute__((ext_vector_type(8)));
typedef float f32x4 __attribute__((ext_vector_type(4)));

#define DMODEL 1024
#define NH 16
#define DH 64
#define BB 2
#define TT 2048
#define MM 4096   // BB*TT
#define NQKV 3072
#define KVB 64    // attention key-tile

// Q pre-scale: Dh^-0.5 * log2(e) -> scores land in log2 domain (P = v_exp_f32 direct)
#define QSCALE 0.18033688011112042f

static __device__ __forceinline__ u16 f2bf(float f) {
  u32 u = __float_as_uint(f);
  u = (u + 0x7FFFu + ((u >> 16) & 1u)) >> 16;  // RNE
  return (u16)u;
}

static __device__ __forceinline__ u32 pk2bf(float a, float b) {
  u16 ua = __builtin_bit_cast(u16, (__bf16)a);
  u16 ub = __builtin_bit_cast(u16, (__bf16)b);
  return (u32)ua | ((u32)ub << 16);
}

static __device__ __forceinline__ float fexp2(float x) {
#if __has_builtin(__builtin_amdgcn_exp2f)
  return __builtin_amdgcn_exp2f(x);
#else
  float r; asm("v_exp_f32 %0, %1" : "=v"(r) : "v"(x)); return r;
#endif
}

static __device__ __forceinline__ float max3f(float a, float b, float c) {
  return fmaxf(fmaxf(a, b), c);  // fuses to v_max3_f32
}

static __device__ __forceinline__ void gload16(const u16* g, u16* l) {
  __builtin_amdgcn_global_load_lds(
      (const __attribute__((address_space(1))) void*)g,
      (__attribute__((address_space(3))) void*)l, 16, 0, 0);
}

// Fused f32->bf16 convert: x | wqkv | wproj (dst regions contiguous in ws).
#define N4X  (MM * DMODEL / 4)
#define N4W  (NQKV * DMODEL / 4)
#define N4P  (DMODEL * DMODEL / 4)
__global__ __launch_bounds__(256) void cvt_all(const float* __restrict__ x,
                                               const float* __restrict__ wqkv,
                                               const float* __restrict__ wproj,
                                               u16* __restrict__ dst) {
  int i = blockIdx.x * 256 + threadIdx.x;
  const float* src;
  int j = i;
  if (i < N4X) {
    src = x;
  } else if (i < N4X + N4W) {
    src = wqkv; j = i - N4X;
  } else {
    src = wproj; j = i - (N4X + N4W);
  }
  float4 v = reinterpret_cast<const float4*>(src)[j];
  ushort4 o;
  o.x = f2bf(v.x); o.y = f2bf(v.y); o.z = f2bf(v.z); o.w = f2bf(v.w);
  reinterpret_cast<ushort4*>(dst)[i] = o;
}

// ---------- GEMM: 128x128 tile, K=1024, 2-phase pipelined (round-5 form) ----------
static __device__ __forceinline__ void gemm_stage(
    const u16* __restrict__ A, const u16* __restrict__ B, u16* As, u16* Bs,
    int r0, int o0, int r1, int o1, int c0, int c1, int kcol) {
  gload16(A + (size_t)r0 * DMODEL + kcol + o0, As + c0 * 8);
  gload16(A + (size_t)r1 * DMODEL + kcol + o1, As + c1 * 8);
  gload16(B + (size_t)r0 * DMODEL + kcol + o0, Bs + c0 * 8);
  gload16(B + (size_t)r1 * DMODEL + kcol + o1, Bs + c1 * 8);
}

static __device__ __forceinline__ void gemm128_mainloop(
    const u16* __restrict__ Abase, const u16* __restrict__ Bbase,
    u16* As, u16* Bs, f32x4 (&acc)[4][4]) {
  const int tid = threadIdx.x;
  const int lane = tid & 63;
  const int w = tid >> 6;
  const int rowg = lane >> 4, col = lane & 15;
  const int wm = w >> 1, wn = w & 1;
  const int c0 = tid, c1 = tid + 256;
  const int r0 = c0 >> 2, o0 = (c0 & 3) * 8;
  const int r1 = c1 >> 2, o1 = (c1 & 3) * 8;

  gemm_stage(Abase, Bbase, As, Bs, r0, o0, r1, o1, c0, c1, 0);
  asm volatile("s_waitcnt vmcnt(0)" ::: "memory");
  __builtin_amdgcn_s_barrier();

  int sel = 0;
  for (int kt = 0; kt < DMODEL / 32; ++kt) {
    const int kn = ((kt + 1) & (DMODEL / 32 - 1)) * 32;
    const int ns = sel ^ 1;
    gemm_stage(Abase, Bbase, As + ns * 4096, Bs + ns * 4096, r0, o0, r1, o1, c0, c1, kn);
    const u16* as = As + sel * 4096;
    const u16* bs = Bs + sel * 4096;
    bf16x8 af[4], bfr[4];
#pragma unroll
    for (int i = 0; i < 4; ++i)
      af[i] = *reinterpret_cast<const bf16x8*>(as + (wm * 64 + i * 16 + col) * 32 + rowg * 8);
#pragma unroll
    for (int j = 0; j < 4; ++j)
      bfr[j] = *reinterpret_cast<const bf16x8*>(bs + (wn * 64 + j * 16 + col) * 32 + rowg * 8);
#pragma unroll
    for (int i = 0; i < 4; ++i)
#pragma unroll
      for (int j = 0; j < 4; ++j)
        acc[i][j] = __builtin_amdgcn_mfma_f32_16x16x32_bf16(af[i], bfr[j], acc[i][j], 0, 0, 0);
    asm volatile("s_waitcnt vmcnt(0)" ::: "memory");
    __builtin_amdgcn_s_barrier();
    sel = ns;
  }
}

// QKV projection: C[m,n] = x[m,:] . Wqkv[n,:]; scatter to q/k/vt, q pre-scaled.
__global__ __launch_bounds__(256, 3) void qkv_gemm(
    const u16* __restrict__ xb, const u16* __restrict__ wb,
    u16* __restrict__ qb, u16* __restrict__ kb, u16* __restrict__ vtb) {
  __shared__ u16 As[2 * 128 * 32];
  __shared__ u16 Bs[2 * 128 * 32];
  f32x4 acc[4][4];
#pragma unroll
  for (int i = 0; i < 4; ++i)
#pragma unroll
    for (int j = 0; j < 4; ++j) acc[i][j] = (f32x4){0.f, 0.f, 0.f, 0.f};
  gemm128_mainloop(xb + (size_t)blockIdx.y * 128 * DMODEL,
                   wb + (size_t)blockIdx.x * 128 * DMODEL, As, Bs, acc);
  const int lane = threadIdx.x & 63, w = threadIdx.x >> 6;
  const int rowg = lane >> 4, col = lane & 15, wm = w >> 1, wn = w & 1;
#pragma unroll
  for (int i = 0; i < 4; ++i) {
#pragma unroll
    for (int j = 0; j < 4; ++j) {
#pragma unroll
      for (int r = 0; r < 4; ++r) {
        int m = blockIdx.y * 128 + wm * 64 + i * 16 + rowg * 4 + r;
        int n = blockIdx.x * 128 + wn * 64 + j * 16 + col;
        int b = m >> 11, t = m & (TT - 1);
        int s = n >> 10, h = (n >> 6) & 15, d = n & 63;
        int bh = b * NH + h;
        float v = acc[i][j][r];
        if (s == 0)      qb[((size_t)bh * TT + t) * DH + d] = f2bf(v * QSCALE);
        else if (s == 1) kb[((size_t)bh * TT + t) * DH + d] = f2bf(v);
        else             vtb[((size_t)bh * DH + d) * TT + t] = f2bf(v);
      }
    }
  }
}

// Output projection: out[m,n] = ob[m,:] . Wproj[n,:], f32 out.
__global__ __launch_bounds__(256, 3) void proj_gemm(
    const u16* __restrict__ ab, const u16* __restrict__ wb, float* __restrict__ out) {
  __shared__ u16 As[2 * 128 * 32];
  __shared__ u16 Bs[2 * 128 * 32];
  f32x4 acc[4][4];
#pragma unroll
  for (int i = 0; i < 4; ++i)
#pragma unroll
    for (int j = 0; j < 4; ++j) acc[i][j] = (f32x4){0.f, 0.f, 0.f, 0.f};
  gemm128_mainloop(ab + (size_t)blockIdx.y * 128 * DMODEL,
                   wb + (size_t)blockIdx.x * 128 * DMODEL, As, Bs, acc);
  const int lane = threadIdx.x & 63, w = threadIdx.x >> 6;
  const int rowg = lane >> 4, col = lane & 15, wm = w >> 1, wn = w & 1;
#pragma unroll
  for (int i = 0; i < 4; ++i) {
#pragma unroll
    for (int j = 0; j < 4; ++j) {
#pragma unroll
      for (int r = 0; r < 4; ++r) {
        int m = blockIdx.y * 128 + wm * 64 + i * 16 + rowg * 4 + r;
        int n = blockIdx.x * 128 + wn * 64 + j * 16 + col;
        out[(size_t)m * DMODEL + n] = acc[i][j][r];
      }
    }
  }
}

// ---------- Flash attention: 512 threads = 8 waves x 16 q-rows (2x occupancy), ----------
// ---------- swapped-operand, log2 softmax, 2-buf K/V pipeline, raw barriers ----------
static __device__ __forceinline__ void attn_stage(
    const u16* __restrict__ kbase, const u16* __restrict__ vbase,
    int kt, u16* KsSel, u16* VsSel, int tid) {
  // 512 threads x 1 chunk each: K tile 8KB
  int row = tid >> 3;
  int bI = (tid & 7) * 16;
  gload16(kbase + kt * (KVB * DH) + row * DH + ((bI ^ ((row & 7) << 4)) >> 1), KsSel + tid * 8);
  // V tile 8KB (row = d)
  gload16(vbase + (size_t)row * TT + kt * KVB + ((bI ^ ((row & 7) << 4)) >> 1), VsSel + tid * 8);
}

__global__ __launch_bounds__(512, 2) void attn_kernel(
    const u16* __restrict__ qb, const u16* __restrict__ kb,
    const u16* __restrict__ vtb, const unsigned char* __restrict__ mask,
    u16* __restrict__ ob) {
  __shared__ u16 Ks[2][KVB * DH];      // [key][d], swizzled, 2 x 8KB
  __shared__ u16 Vs[2][DH * KVB];      // [d][key], swizzled, 2 x 8KB
  __shared__ u16 Pl[8][16 * KVB];      // per-wave [q][key], swizzled, 8 x 2KB
  __shared__ unsigned char maskb[TT];
  __shared__ u32 mflag;

  const int tid = threadIdx.x;
  const int lane = tid & 63, w = tid >> 6;
  const int rowg = lane >> 4, col = lane & 15;
  const int qt = blockIdx.x, bh = blockIdx.y;
  const int b = bh >> 4;

  if (tid == 0) mflag = 0;
  __syncthreads();

  {  // 4 mask bytes/thread; tile index = (tid*4)/64 = tid>>4
    u32 m0 = reinterpret_cast<const u32*>(mask + (size_t)b * TT)[tid];
    *reinterpret_cast<u32*>(maskb + tid * 4) = m0;
    if (m0) atomicOr(&mflag, 1u << (tid >> 4));
  }

  const int qrow0 = qt * 128 + w * 16;
  const u16* qptr = qb + ((size_t)bh * TT + qrow0) * DH;
  bf16x8 a_q[2];  // [ds] — B-operand frags: col = query, k-slice = d
#pragma unroll
  for (int ds = 0; ds < 2; ++ds)
    a_q[ds] = *reinterpret_cast<const bf16x8*>(qptr + col * DH + ds * 32 + rowg * 8);

  f32x4 acc_o[4];          // [df]: query = col, d = df*16 + rowg*4 + r
  float m_run = -1e30f, l_run = 0.f;  // log2-domain running max / sum
#pragma unroll
  for (int df = 0; df < 4; ++df) acc_o[df] = (f32x4){0.f, 0.f, 0.f, 0.f};

  const u16* kbase = kb + (size_t)bh * TT * DH;
  const u16* vbase = vtb + (size_t)bh * DH * TT;
  u16* pw = Pl[w];

  attn_stage(kbase, vbase, 0, Ks[0], Vs[0], tid);
  __syncthreads();  // drains prologue stage + publishes mask/mflag
  const u32 fm = mflag;

  int cur = 0;
  for (int t = 0; t < TT / KVB; ++t) {
    const int tn = (t + 1) & (TT / KVB - 1);  // wrap: in-bounds, uniform vm count
    attn_stage(kbase, vbase, tn, Ks[cur ^ 1], Vs[cur ^ 1], tid);

    // ---- S^T = K . Q^T : sc[kf], key = kf*16 + rowg*4 + r, query = col ----
    f32x4 sc[4];
#pragma unroll
    for (int kf = 0; kf < 4; ++kf) sc[kf] = (f32x4){0.f, 0.f, 0.f, 0.f};
    const u16* ks = Ks[cur];
#pragma unroll
    for (int ds = 0; ds < 2; ++ds) {
      bf16x8 ak[4];
#pragma unroll
      for (int kf = 0; kf < 4; ++kf) {
        int krow = kf * 16 + col;
        ak[kf] = *reinterpret_cast<const bf16x8*>(
            ks + krow * DH + (((ds * 64 + rowg * 16) ^ ((krow & 7) << 4)) >> 1));
      }
#pragma unroll
      for (int kf = 0; kf < 4; ++kf)
        sc[kf] = __builtin_amdgcn_mfma_f32_16x16x32_bf16(ak[kf], a_q[ds], sc[kf], 0, 0, 0);
    }

    if (fm & (1u << t)) {  // rare path: per-key additive mask (log2 domain ok)
#pragma unroll
      for (int kf = 0; kf < 4; ++kf)
#pragma unroll
        for (int r = 0; r < 4; ++r)
          sc[kf][r] += maskb[t * KVB + kf * 16 + rowg * 4 + r] ? -1e30f : 0.f;
    }

    // ---- online softmax: lane-local max (v_max3) + 2 shuffles; defer-rescale THR=8 ----
    {
      float t0 = max3f(sc[0][0], sc[0][1], sc[0][2]);
      float t1 = max3f(sc[0][3], sc[1][0], sc[1][1]);
      float t2 = max3f(sc[1][2], sc[1][3], sc[2][0]);
      float t3 = max3f(sc[2][1], sc[2][2], sc[2][3]);
      float t4 = max3f(sc[3][0], sc[3][1], sc[3][2]);
      float mx = fmaxf(max3f(t0, t1, t2), max3f(t3, t4, sc[3][3]));
      mx = fmaxf(mx, __shfl_xor(mx, 16, 64));
      mx = fmaxf(mx, __shfl_xor(mx, 32, 64));
      if (__any(mx > m_run + 8.0f)) {   // T13: rescale only on real max growth
        float mn = fmaxf(m_run, mx);
        float corr = fexp2(m_run - mn);  // 2^(old-new); first tile -> 0
        m_run = mn;
        l_run *= corr;
#pragma unroll
        for (int df = 0; df < 4; ++df) acc_o[df] *= corr;
      }
      const float mc = m_run;

      const int sw = (col & 7) << 4;
      u16* prow = pw + col * KVB;
      float rs = 0.f;
#pragma unroll
      for (int kf = 0; kf < 4; ++kf) {
        float p0 = fexp2(sc[kf][0] - mc);
        float p1 = fexp2(sc[kf][1] - mc);
        float p2 = fexp2(sc[kf][2] - mc);
        float p3 = fexp2(sc[kf][3] - mc);
        rs += (p0 + p1) + (p2 + p3);
        uint2 pk;
        pk.x = pk2bf(p0, p1);
        pk.y = pk2bf(p2, p3);
        int bI = kf * 32 + rowg * 8;
        *reinterpret_cast<uint2*>(prow + ((bI ^ sw) >> 1)) = pk;  // ds_write_b64
      }
      rs += __shfl_xor(rs, 16, 64);
      rs += __shfl_xor(rs, 32, 64);
      l_run += rs;
    }
    asm volatile("s_waitcnt lgkmcnt(0)" ::: "memory");
    __builtin_amdgcn_sched_barrier(0);

    // ---- O^T += V^T . P^T ----
    const u16* vs = Vs[cur];
    __builtin_amdgcn_s_setprio(1);
#pragma unroll
    for (int ksI = 0; ksI < 2; ++ksI) {
      bf16x8 bp = *reinterpret_cast<const bf16x8*>(
          pw + col * KVB + (((ksI * 64 + rowg * 16) ^ ((col & 7) << 4)) >> 1));
#pragma unroll
      for (int df = 0; df < 4; ++df) {
        int vrow = df * 16 + col;
        bf16x8 bv = *reinterpret_cast<const bf16x8*>(
            vs + vrow * KVB + (((ksI * 64 + rowg * 16) ^ ((vrow & 7) << 4)) >> 1));
        acc_o[df] = __builtin_amdgcn_mfma_f32_16x16x32_bf16(bv, bp, acc_o[df], 0, 0, 0);
      }
    }
    __builtin_amdgcn_s_setprio(0);

    asm volatile("s_waitcnt vmcnt(0)" ::: "memory");
    __builtin_amdgcn_s_barrier();
    cur ^= 1;
  }

  const int h = bh & 15;
  {
    float inv = 1.f / l_run;
    int tq = qrow0 + col;
    size_t rowoff = ((size_t)(b * TT + tq)) * DMODEL + h * DH + rowg * 4;
#pragma unroll
    for (int df = 0; df < 4; ++df) {
      ushort4 o4;
      o4.x = f2bf(acc_o[df][0] * inv);
      o4.y = f2bf(acc_o[df][1] * inv);
      o4.z = f2bf(acc_o[df][2] * inv);
      o4.w = f2bf(acc_o[df][3] * inv);
      *reinterpret_cast<ushort4*>(ob + rowoff + df * 16) = o4;
    }
  }
}

extern "C" void kernel_launch(void* const* d_in, const int* in_sizes, int n_in,
                              void* d_out, int out_size, void* d_ws, size_t ws_size,
                              hipStream_t stream) {
  const float* x = (const float*)d_in[0];
  const unsigned char* mask = (const unsigned char*)d_in[1];
  const float* wqkv = (const float*)d_in[2];
  const float* wproj = (const float*)d_in[3];
  float* out = (float*)d_out;

  u16* xb     = (u16*)d_ws;
  u16* wqkvb  = xb    + (size_t)MM * DMODEL;
  u16* wprojb = wqkvb + (size_t)NQKV * DMODEL;
  u16* qb     = wprojb + (size_t)DMODEL * DMODEL;
  u16* kb     = qb + (size_t)MM * DMODEL;
  u16* vtb    = kb + (size_t)MM * DMODEL;
  u16* ob     = vtb + (size_t)MM * DMODEL;

  cvt_all<<<(N4X + N4W + N4P) / 256, 256, 0, stream>>>(x, wqkv, wproj, xb);
  qkv_gemm<<<dim3(NQKV / 128, MM / 128), 256, 0, stream>>>(xb, wqkvb, qb, kb, vtb);
  attn_kernel<<<dim3(TT / 128, BB * NH), 512, 0, stream>>>(qb, kb, vtb, mask, ob);
  proj_gemm<<<dim3(DMODEL / 128, MM / 128), 256, 0, stream>>>(ob, wprojb, out);
}